// Round 1
// baseline (1168.131 us; speedup 1.0000x reference)
//
#include <hip/hip_runtime.h>
#include <math.h>

#define HC 128
#define NSLOPE 0.2f

__device__ __forceinline__ float lrelu(float v){ return v > 0.f ? v : NSLOPE * v; }

// ----------------- CSR build (dst-sorted) -----------------
__global__ void count_kernel(const int* __restrict__ ei, int* __restrict__ cnt, int E){
    int e = blockIdx.x * blockDim.x + threadIdx.x;
    if (e < E) atomicAdd(&cnt[ei[E + e]], 1);
}

__global__ void scan_kernel(const int* __restrict__ deg, int* __restrict__ rowptr, int n){
    const int T = 1024;
    int t = threadIdx.x;
    int per = (n + T - 1) / T;
    int start = t * per; if (start > n) start = n;
    int end = start + per; if (end > n) end = n;
    int sum = 0;
    for (int i = start; i < end; ++i) sum += deg[i];
    __shared__ int ps[T];
    ps[t] = sum;
    __syncthreads();
    for (int off = 1; off < T; off <<= 1){
        int v = (t >= off) ? ps[t - off] : 0;
        __syncthreads();
        ps[t] += v;
        __syncthreads();
    }
    int run = (t == 0) ? 0 : ps[t - 1];
    for (int i = start; i < end; ++i){ rowptr[i] = run; run += deg[i]; }
    if (t == T - 1) rowptr[n] = run;
}

__global__ void scatter_kernel(const int* __restrict__ ei, const int* __restrict__ rowptr,
                               int* __restrict__ cursor, int* __restrict__ colsrc, int E){
    int e = blockIdx.x * blockDim.x + threadIdx.x;
    if (e < E){
        int d = ei[E + e];
        int pos = rowptr[d] + atomicAdd(&cursor[d], 1);
        colsrc[pos] = ei[e];
    }
}

// ----------------- node encoder: h = relu(x@w1+b1)@w2+b2 -----------------
__global__ __launch_bounds__(128) void node_enc_kernel(
        const float* __restrict__ x, const float* __restrict__ w1, const float* __restrict__ b1,
        const float* __restrict__ w2, const float* __restrict__ b2,
        float* __restrict__ h, int n)
{
    __shared__ float ts[HC][128];       // ts[k][t]: thread t's hidden vector (bank = t%32, 2-way free)
    int t = threadIdx.x;
    int node = blockIdx.x * 128 + t;
    bool valid = node < n;
    float xr[32];
    if (valid){
        const float4* r = (const float4*)(x + (size_t)node * 32);
        #pragma unroll
        for (int q = 0; q < 8; ++q){ float4 v = r[q]; xr[q*4]=v.x; xr[q*4+1]=v.y; xr[q*4+2]=v.z; xr[q*4+3]=v.w; }
    } else {
        #pragma unroll
        for (int q = 0; q < 32; ++q) xr[q] = 0.f;
    }
    #pragma unroll
    for (int jt = 0; jt < HC; jt += 32){
        float acc[32];
        #pragma unroll
        for (int c = 0; c < 32; ++c) acc[c] = b1[jt + c];
        #pragma unroll
        for (int k = 0; k < 32; ++k){
            float xv = xr[k];
            const float* wr = w1 + k * HC + jt;
            #pragma unroll
            for (int c = 0; c < 32; ++c) acc[c] = fmaf(xv, wr[c], acc[c]);
        }
        #pragma unroll
        for (int c = 0; c < 32; ++c) ts[jt + c][t] = fmaxf(acc[c], 0.f);
    }
    // stage 2: each thread reads only its own LDS column -> no sync needed
    #pragma unroll
    for (int jt = 0; jt < HC; jt += 32){
        float acc[32];
        #pragma unroll
        for (int c = 0; c < 32; ++c) acc[c] = b2[jt + c];
        for (int k = 0; k < HC; ++k){
            float tv = ts[k][t];
            const float* wr = w2 + k * HC + jt;
            #pragma unroll
            for (int c = 0; c < 32; ++c) acc[c] = fmaf(tv, wr[c], acc[c]);
        }
        if (valid){
            float4* o = (float4*)(h + (size_t)node * HC + jt);
            #pragma unroll
            for (int q = 0; q < 8; ++q) o[q] = make_float4(acc[q*4], acc[q*4+1], acc[q*4+2], acc[q*4+3]);
        }
    }
}

// ----------------- per-layer: h1 = h@w, asrc/adst = <h1, att> -----------------
__global__ __launch_bounds__(128) void gemm_att_kernel(
        const float* __restrict__ h, const float* __restrict__ w,
        const float* __restrict__ att_s, const float* __restrict__ att_d,
        float* __restrict__ h1, float* __restrict__ asrc, float* __restrict__ adst, int n)
{
    __shared__ float hs[HC][128];
    int t = threadIdx.x;
    int node = blockIdx.x * 128 + t;
    bool valid = node < n;
    if (valid){
        const float4* r = (const float4*)(h + (size_t)node * HC);
        #pragma unroll
        for (int q = 0; q < 32; ++q){ float4 v = r[q]; hs[q*4][t]=v.x; hs[q*4+1][t]=v.y; hs[q*4+2][t]=v.z; hs[q*4+3][t]=v.w; }
    } else {
        #pragma unroll
        for (int q = 0; q < HC; ++q) hs[q][t] = 0.f;
    }
    float as0=0.f, as1=0.f, ad0=0.f, ad1=0.f;
    #pragma unroll
    for (int jt = 0; jt < HC; jt += 32){
        float acc[32];
        #pragma unroll
        for (int c = 0; c < 32; ++c) acc[c] = 0.f;
        for (int k = 0; k < HC; ++k){
            float hv = hs[k][t];
            const float* wr = w + k * HC + jt;        // wave-uniform -> scalar loads
            #pragma unroll
            for (int c = 0; c < 32; ++c) acc[c] = fmaf(hv, wr[c], acc[c]);
        }
        float sa = 0.f, sd = 0.f;
        #pragma unroll
        for (int c = 0; c < 32; ++c){
            sa = fmaf(acc[c], att_s[jt + c], sa);
            sd = fmaf(acc[c], att_d[jt + c], sd);
        }
        if (jt < 64){ as0 += sa; ad0 += sd; } else { as1 += sa; ad1 += sd; }
        if (valid){
            float4* o = (float4*)(h1 + (size_t)node * HC + jt);
            #pragma unroll
            for (int q = 0; q < 8; ++q) o[q] = make_float4(acc[q*4], acc[q*4+1], acc[q*4+2], acc[q*4+3]);
        }
    }
    if (valid){
        asrc[(size_t)node*2]   = as0; asrc[(size_t)node*2+1] = as1;
        adst[(size_t)node*2]   = ad0; adst[(size_t)node*2+1] = ad1;
    }
}

// ----------------- aggregation: out = relu( (Σ ex·h'[src]) / (Σ ex) + b ) -----------------
__global__ __launch_bounds__(64) void aggregate_kernel(
        const float* __restrict__ h1, const float* __restrict__ asrc, const float* __restrict__ adst,
        const int* __restrict__ rowptr, const int* __restrict__ colsrc,
        const float* __restrict__ bias, float* __restrict__ hout, int n)
{
    int i = blockIdx.x;
    if (i >= n) return;
    int t = threadIdx.x;              // 64 threads, 2 channels each
    int head = t >> 5;                // channels [2t,2t+1] belong to head (2t)>>6 == t>>5
    float ad = adst[(size_t)i*2 + head];
    // self loop (GATConv add_self_loops=True)
    float ex = __expf(lrelu(asrc[(size_t)i*2 + head] + ad));
    float2 hv = ((const float2*)(h1 + (size_t)i * HC))[t];
    float acc0 = ex * hv.x, acc1 = ex * hv.y, D = ex;
    int e  = rowptr[i];
    int e1 = rowptr[i + 1];
    for (; e < e1; ++e){
        int s = colsrc[e];                                     // wave-uniform
        float exx = __expf(lrelu(asrc[(size_t)s*2 + head] + ad));
        float2 hh = ((const float2*)(h1 + (size_t)s * HC))[t]; // coalesced 512B gather
        acc0 = fmaf(exx, hh.x, acc0);
        acc1 = fmaf(exx, hh.y, acc1);
        D += exx;
    }
    float rD = 1.0f / D;
    float o0 = fmaxf(fmaf(acc0, rD, 0.f) + bias[2*t],     0.f);
    float o1 = fmaxf(fmaf(acc1, rD, 0.f) + bias[2*t + 1], 0.f);
    ((float2*)(hout + (size_t)i * HC))[t] = make_float2(o0, o1);
}

// ----------------- graph mean -----------------
__global__ void mean_kernel(const float* __restrict__ h, float* __restrict__ g, int n){
    int c = threadIdx.x;              // 128
    float acc = 0.f;
    for (int i = blockIdx.x; i < n; i += gridDim.x)
        acc += h[(size_t)i * HC + c];
    atomicAdd(&g[c], acc);
}

// ----------------- vuln head: sigmoid(relu(h@wv1+bv1)@wv2+bv2) -----------------
__global__ __launch_bounds__(128) void vuln_kernel(
        const float* __restrict__ h, const float* __restrict__ wv1, const float* __restrict__ bv1,
        const float* __restrict__ wv2, const float* __restrict__ bv2,
        float* __restrict__ out, int n)
{
    __shared__ float hs[HC][128];
    int t = threadIdx.x;
    int node = blockIdx.x * 128 + t;
    if (node >= n) return;
    const float4* r = (const float4*)(h + (size_t)node * HC);
    #pragma unroll
    for (int q = 0; q < 32; ++q){ float4 v = r[q]; hs[q*4][t]=v.x; hs[q*4+1][t]=v.y; hs[q*4+2][t]=v.z; hs[q*4+3][t]=v.w; }
    float tot = bv2[0];
    #pragma unroll
    for (int jt = 0; jt < 64; jt += 16){
        float acc[16];
        #pragma unroll
        for (int c = 0; c < 16; ++c) acc[c] = bv1[jt + c];
        for (int k = 0; k < HC; ++k){
            float hv = hs[k][t];
            const float* wr = wv1 + k * 64 + jt;
            #pragma unroll
            for (int c = 0; c < 16; ++c) acc[c] = fmaf(hv, wr[c], acc[c]);
        }
        #pragma unroll
        for (int c = 0; c < 16; ++c) tot = fmaf(fmaxf(acc[c], 0.f), wv2[jt + c], tot);
    }
    out[1 + node] = 1.0f / (1.0f + __expf(-tot));
}

// ----------------- path head (1 block) -----------------
__global__ __launch_bounds__(128) void path_kernel(
        const float* __restrict__ h, const float* __restrict__ g,
        const float* __restrict__ wp1, const float* __restrict__ bp1,
        const float* __restrict__ wp2, const float* __restrict__ bp2,
        const float* __restrict__ wp3, const float* __restrict__ bp3,
        float* __restrict__ out, int n)
{
    __shared__ float pc[256];
    __shared__ float p1[HC];
    __shared__ float p2[64];
    int t = threadIdx.x;              // 128
    pc[t]       = h[t];               // h[0,:]
    pc[128 + t] = g[t] * (1.0f / (float)n);
    __syncthreads();
    float a = bp1[t];
    for (int k = 0; k < 256; ++k) a = fmaf(pc[k], wp1[k * HC + t], a);
    p1[t] = fmaxf(a, 0.f);
    __syncthreads();
    if (t < 64){
        float a2 = bp2[t];
        for (int k = 0; k < HC; ++k) a2 = fmaf(p1[k], wp2[k * 64 + t], a2);
        p2[t] = fmaxf(a2, 0.f);
    }
    __syncthreads();
    if (t == 0){
        float a3 = bp3[0];
        for (int k = 0; k < 64; ++k) a3 = fmaf(p2[k], wp3[k], a3);
        out[0] = 1.0f / (1.0f + __expf(-a3));
        out[1 + n] = 0.f;             // esc = 0
    }
}

extern "C" void kernel_launch(void* const* d_in, const int* in_sizes, int n_in,
                              void* d_out, int out_size, void* d_ws, size_t ws_size,
                              hipStream_t stream)
{
    const float* x    = (const float*)d_in[0];
    const int*   ei   = (const int*)d_in[1];
    // d_in[2] edge_attr: computed-but-ignored by reference -> never touched
    const float* w_n1 = (const float*)d_in[3];
    const float* b_n1 = (const float*)d_in[4];
    const float* w_n2 = (const float*)d_in[5];
    const float* b_n2 = (const float*)d_in[6];
    // d_in[7..8] edge encoder: unused
    const float* conv_w = (const float*)d_in[9];
    const float* att_s  = (const float*)d_in[10];
    const float* att_d  = (const float*)d_in[11];
    const float* conv_b = (const float*)d_in[12];
    const float* wp1 = (const float*)d_in[13];
    const float* bp1 = (const float*)d_in[14];
    const float* wp2 = (const float*)d_in[15];
    const float* bp2 = (const float*)d_in[16];
    const float* wp3 = (const float*)d_in[17];
    const float* bp3 = (const float*)d_in[18];
    const float* wv1 = (const float*)d_in[19];
    const float* bv1 = (const float*)d_in[20];
    const float* wv2 = (const float*)d_in[21];
    const float* bv2 = (const float*)d_in[22];

    const int N = in_sizes[0] / 32;
    const int E = in_sizes[1] / 2;
    float* out = (float*)d_out;

    char* ws = (char*)d_ws;
    size_t off = 0;
    auto take = [&](size_t bytes) -> char* {
        char* p = ws + off;
        off += (bytes + 255) & ~(size_t)255;
        return p;
    };
    float* hA    = (float*)take((size_t)N * HC * 4);
    float* hB    = (float*)take((size_t)N * HC * 4);
    float* asrc  = (float*)take((size_t)N * 2 * 4);
    float* adst  = (float*)take((size_t)N * 2 * 4);
    int*   rowptr= (int*)take((size_t)(N + 1) * 4);
    int*   cursor= (int*)take((size_t)N * 4);
    int*   colsrc= (int*)take((size_t)E * 4);
    float* g     = (float*)take(HC * 4);

    // --- CSR build (dst-sorted; reused across the 3 layers) ---
    hipMemsetAsync(cursor, 0, (size_t)N * 4, stream);
    count_kernel<<<(E + 255) / 256, 256, 0, stream>>>(ei, cursor, E);
    scan_kernel<<<1, 1024, 0, stream>>>(cursor, rowptr, N);
    hipMemsetAsync(cursor, 0, (size_t)N * 4, stream);
    scatter_kernel<<<(E + 255) / 256, 256, 0, stream>>>(ei, rowptr, cursor, colsrc, E);

    int nblk = (N + 127) / 128;
    node_enc_kernel<<<nblk, 128, 0, stream>>>(x, w_n1, b_n1, w_n2, b_n2, hA, N);

    for (int l = 0; l < 3; ++l){
        gemm_att_kernel<<<nblk, 128, 0, stream>>>(
            hA, conv_w + (size_t)l * HC * HC,
            att_s + (size_t)l * HC, att_d + (size_t)l * HC,
            hB, asrc, adst, N);
        aggregate_kernel<<<N, 64, 0, stream>>>(
            hB, asrc, adst, rowptr, colsrc, conv_b + (size_t)l * HC, hA, N);
    }

    hipMemsetAsync(g, 0, HC * 4, stream);
    mean_kernel<<<256, 128, 0, stream>>>(hA, g, N);
    vuln_kernel<<<nblk, 128, 0, stream>>>(hA, wv1, bv1, wv2, bv2, out, N);
    path_kernel<<<1, 128, 0, stream>>>(hA, g, wp1, bp1, wp2, bp2, wp3, bp3, out, N);
}

// Round 2
// 588.881 us; speedup vs baseline: 1.9836x; 1.9836x over previous
//
#include <hip/hip_runtime.h>
#include <math.h>

#define HC 128
#define NSLOPE 0.2f

__device__ __forceinline__ float lrelu(float v){ return v > 0.f ? v : NSLOPE * v; }

// ----------------- CSR build (dst-sorted) -----------------
__global__ void count_kernel(const int* __restrict__ ei, int* __restrict__ cnt, int E){
    int e = blockIdx.x * blockDim.x + threadIdx.x;
    if (e < E) atomicAdd(&cnt[ei[E + e]], 1);
}

__global__ void scan_kernel(const int* __restrict__ deg, int* __restrict__ rowptr, int n){
    const int T = 1024;
    int t = threadIdx.x;
    int per = (n + T - 1) / T;
    int start = t * per; if (start > n) start = n;
    int end = start + per; if (end > n) end = n;
    int sum = 0;
    for (int i = start; i < end; ++i) sum += deg[i];
    __shared__ int ps[T];
    ps[t] = sum;
    __syncthreads();
    for (int off = 1; off < T; off <<= 1){
        int v = (t >= off) ? ps[t - off] : 0;
        __syncthreads();
        ps[t] += v;
        __syncthreads();
    }
    int run = (t == 0) ? 0 : ps[t - 1];
    for (int i = start; i < end; ++i){ rowptr[i] = run; run += deg[i]; }
    if (t == T - 1) rowptr[n] = run;
}

__global__ void scatter_kernel(const int* __restrict__ ei, const int* __restrict__ rowptr,
                               int* __restrict__ cursor, int* __restrict__ colsrc, int E){
    int e = blockIdx.x * blockDim.x + threadIdx.x;
    if (e < E){
        int d = ei[E + e];
        int pos = rowptr[d] + atomicAdd(&cursor[d], 1);
        colsrc[pos] = ei[e];
    }
}

// ----------------- node encoder stage 1: hid = relu(x@w1+b1), K=32 -----------------
__global__ __launch_bounds__(256) void enc1_kernel(
        const float* __restrict__ x, const float* __restrict__ w1, const float* __restrict__ b1,
        float* __restrict__ hid, int n)
{
    __shared__ float As[32][132];   // As[k][m], +4 pad kills write conflicts
    __shared__ float Bs[32][128];
    int t = threadIdx.x;
    int m0 = blockIdx.x * 128;
    int tm = t >> 4, tn = t & 15;

    #pragma unroll
    for (int i = 0; i < 4; ++i){            // A-tile: 128 rows x 32 k (transpose into LDS)
        int f = i * 256 + t;
        int row = f >> 3, kq = f & 7;
        int gr = m0 + row; if (gr > n - 1) gr = n - 1;
        float4 v = *(const float4*)(x + (size_t)gr * 32 + kq * 4);
        As[kq*4+0][row] = v.x; As[kq*4+1][row] = v.y; As[kq*4+2][row] = v.z; As[kq*4+3][row] = v.w;
    }
    #pragma unroll
    for (int i = 0; i < 4; ++i){            // B: 32x128
        int f = i * 256 + t;
        int kk = f >> 5, nq = f & 31;
        *(float4*)&Bs[kk][nq*4] = *(const float4*)(w1 + (size_t)kk * 128 + nq * 4);
    }
    __syncthreads();

    float acc[8][8];
    #pragma unroll
    for (int i = 0; i < 8; ++i)
        #pragma unroll
        for (int j = 0; j < 8; ++j) acc[i][j] = 0.f;

    #pragma unroll 4
    for (int k = 0; k < 32; ++k){
        float a[8], b[8];
        *(float4*)&a[0] = *(float4*)&As[k][tm*8];
        *(float4*)&a[4] = *(float4*)&As[k][tm*8+4];
        *(float4*)&b[0] = *(float4*)&Bs[k][tn*8];
        *(float4*)&b[4] = *(float4*)&Bs[k][tn*8+4];
        #pragma unroll
        for (int i = 0; i < 8; ++i)
            #pragma unroll
            for (int j = 0; j < 8; ++j) acc[i][j] = fmaf(a[i], b[j], acc[i][j]);
    }

    float bb[8];
    *(float4*)&bb[0] = *(const float4*)(b1 + tn*8);
    *(float4*)&bb[4] = *(const float4*)(b1 + tn*8 + 4);
    #pragma unroll
    for (int i = 0; i < 8; ++i){
        int node = m0 + tm*8 + i;
        if (node < n){
            float o[8];
            #pragma unroll
            for (int j = 0; j < 8; ++j) o[j] = fmaxf(acc[i][j] + bb[j], 0.f);
            *(float4*)(hid + (size_t)node*HC + tn*8)     = *(float4*)&o[0];
            *(float4*)(hid + (size_t)node*HC + tn*8 + 4) = *(float4*)&o[4];
        }
    }
}

// ----------------- main GEMM: C = A@W (+bias); optional fused att dots -----------------
template<bool ATT>
__global__ __launch_bounds__(256) void gemm_main_kernel(
        const float* __restrict__ A, const float* __restrict__ W, const float* __restrict__ bias,
        const float* __restrict__ att_s, const float* __restrict__ att_d,
        float* __restrict__ C, float* __restrict__ asrc, float* __restrict__ adst, int n)
{
    __shared__ float As[32][132];
    __shared__ float Bs[32][128];
    int t = threadIdx.x;
    int m0 = blockIdx.x * 128;
    int tm = t >> 4, tn = t & 15;

    float acc[8][8];
    #pragma unroll
    for (int i = 0; i < 8; ++i)
        #pragma unroll
        for (int j = 0; j < 8; ++j) acc[i][j] = 0.f;

    for (int kc = 0; kc < 4; ++kc){
        int k0 = kc * 32;
        #pragma unroll
        for (int i = 0; i < 4; ++i){        // A chunk 128x32, transposed into LDS
            int f = i * 256 + t;
            int row = f >> 3, kq = f & 7;
            int gr = m0 + row; if (gr > n - 1) gr = n - 1;
            float4 v = *(const float4*)(A + (size_t)gr * HC + k0 + kq * 4);
            As[kq*4+0][row] = v.x; As[kq*4+1][row] = v.y; As[kq*4+2][row] = v.z; As[kq*4+3][row] = v.w;
        }
        #pragma unroll
        for (int i = 0; i < 4; ++i){        // B chunk 32x128
            int f = i * 256 + t;
            int kk = f >> 5, nq = f & 31;
            *(float4*)&Bs[kk][nq*4] = *(const float4*)(W + (size_t)(k0 + kk) * 128 + nq * 4);
        }
        __syncthreads();
        #pragma unroll 4
        for (int k = 0; k < 32; ++k){
            float a[8], b[8];
            *(float4*)&a[0] = *(float4*)&As[k][tm*8];
            *(float4*)&a[4] = *(float4*)&As[k][tm*8+4];
            *(float4*)&b[0] = *(float4*)&Bs[k][tn*8];
            *(float4*)&b[4] = *(float4*)&Bs[k][tn*8+4];
            #pragma unroll
            for (int i = 0; i < 8; ++i)
                #pragma unroll
                for (int j = 0; j < 8; ++j) acc[i][j] = fmaf(a[i], b[j], acc[i][j]);
        }
        __syncthreads();
    }

    float bb[8];
    if (bias){
        *(float4*)&bb[0] = *(const float4*)(bias + tn*8);
        *(float4*)&bb[4] = *(const float4*)(bias + tn*8 + 4);
    } else {
        #pragma unroll
        for (int j = 0; j < 8; ++j) bb[j] = 0.f;
    }
    #pragma unroll
    for (int i = 0; i < 8; ++i){
        int node = m0 + tm*8 + i;
        if (node < n){
            float o[8];
            #pragma unroll
            for (int j = 0; j < 8; ++j) o[j] = acc[i][j] + bb[j];
            *(float4*)(C + (size_t)node*HC + tn*8)     = *(float4*)&o[0];
            *(float4*)(C + (size_t)node*HC + tn*8 + 4) = *(float4*)&o[4];
        }
    }

    if (ATT){
        float ats[8], atd[8];
        *(float4*)&ats[0] = *(const float4*)(att_s + tn*8);
        *(float4*)&ats[4] = *(const float4*)(att_s + tn*8 + 4);
        *(float4*)&atd[0] = *(const float4*)(att_d + tn*8);
        *(float4*)&atd[4] = *(const float4*)(att_d + tn*8 + 4);
        #pragma unroll
        for (int i = 0; i < 8; ++i){
            float sa = 0.f, sd = 0.f;
            #pragma unroll
            for (int j = 0; j < 8; ++j){
                sa = fmaf(acc[i][j], ats[j], sa);
                sd = fmaf(acc[i][j], atd[j], sd);
            }
            sa += __shfl_xor(sa, 1); sa += __shfl_xor(sa, 2); sa += __shfl_xor(sa, 4);
            sd += __shfl_xor(sd, 1); sd += __shfl_xor(sd, 2); sd += __shfl_xor(sd, 4);
            int node = m0 + tm*8 + i;
            if ((tn == 0 || tn == 8) && node < n){
                int head = tn >> 3;
                asrc[(size_t)node*2 + head] = sa;
                adst[(size_t)node*2 + head] = sd;
            }
        }
    }
}

// ----------------- aggregation: out = relu( (Σ ex·h'[src]) / (Σ ex) + b ) -----------------
__global__ __launch_bounds__(64) void aggregate_kernel(
        const float* __restrict__ h1, const float* __restrict__ asrc, const float* __restrict__ adst,
        const int* __restrict__ rowptr, const int* __restrict__ colsrc,
        const float* __restrict__ bias, float* __restrict__ hout, int n)
{
    int i = blockIdx.x;
    if (i >= n) return;
    int t = threadIdx.x;              // 64 threads, 2 channels each
    int head = t >> 5;
    float ad = adst[(size_t)i*2 + head];
    float ex = __expf(lrelu(asrc[(size_t)i*2 + head] + ad));   // self loop
    float2 hv = ((const float2*)(h1 + (size_t)i * HC))[t];
    float acc0 = ex * hv.x, acc1 = ex * hv.y, D = ex;
    int e  = rowptr[i];
    int e1 = rowptr[i + 1];
    for (; e < e1; ++e){
        int s = colsrc[e];
        float exx = __expf(lrelu(asrc[(size_t)s*2 + head] + ad));
        float2 hh = ((const float2*)(h1 + (size_t)s * HC))[t];
        acc0 = fmaf(exx, hh.x, acc0);
        acc1 = fmaf(exx, hh.y, acc1);
        D += exx;
    }
    float rD = 1.0f / D;
    float o0 = fmaxf(fmaf(acc0, rD, 0.f) + bias[2*t],     0.f);
    float o1 = fmaxf(fmaf(acc1, rD, 0.f) + bias[2*t + 1], 0.f);
    ((float2*)(hout + (size_t)i * HC))[t] = make_float2(o0, o1);
}

// ----------------- graph mean -----------------
__global__ void mean_kernel(const float* __restrict__ h, float* __restrict__ g, int n){
    int c = threadIdx.x;              // 128
    float acc = 0.f;
    for (int i = blockIdx.x; i < n; i += gridDim.x)
        acc += h[(size_t)i * HC + c];
    atomicAdd(&g[c], acc);
}

// ----------------- vuln head: sigmoid(relu(h@wv1+bv1)@wv2+bv2), tiled -----------------
__global__ __launch_bounds__(256) void vuln_fused_kernel(
        const float* __restrict__ h, const float* __restrict__ wv1, const float* __restrict__ bv1,
        const float* __restrict__ wv2, const float* __restrict__ bv2,
        float* __restrict__ out, int n)
{
    __shared__ float As[32][132];
    __shared__ float Bs[32][64];
    int t = threadIdx.x;
    int m0 = blockIdx.x * 128;
    int tm = t >> 4, tn = t & 15;

    float acc[8][4];
    #pragma unroll
    for (int i = 0; i < 8; ++i)
        #pragma unroll
        for (int j = 0; j < 4; ++j) acc[i][j] = 0.f;

    for (int kc = 0; kc < 4; ++kc){
        int k0 = kc * 32;
        #pragma unroll
        for (int i = 0; i < 4; ++i){
            int f = i * 256 + t;
            int row = f >> 3, kq = f & 7;
            int gr = m0 + row; if (gr > n - 1) gr = n - 1;
            float4 v = *(const float4*)(h + (size_t)gr * HC + k0 + kq * 4);
            As[kq*4+0][row] = v.x; As[kq*4+1][row] = v.y; As[kq*4+2][row] = v.z; As[kq*4+3][row] = v.w;
        }
        #pragma unroll
        for (int i = 0; i < 2; ++i){        // B chunk 32x64
            int f = i * 256 + t;
            int kk = f >> 4, nq = f & 15;
            *(float4*)&Bs[kk][nq*4] = *(const float4*)(wv1 + (size_t)(k0 + kk) * 64 + nq * 4);
        }
        __syncthreads();
        #pragma unroll 4
        for (int k = 0; k < 32; ++k){
            float a[8], b[4];
            *(float4*)&a[0] = *(float4*)&As[k][tm*8];
            *(float4*)&a[4] = *(float4*)&As[k][tm*8+4];
            *(float4*)&b[0] = *(float4*)&Bs[k][tn*4];
            #pragma unroll
            for (int i = 0; i < 8; ++i)
                #pragma unroll
                for (int j = 0; j < 4; ++j) acc[i][j] = fmaf(a[i], b[j], acc[i][j]);
        }
        __syncthreads();
    }

    float bb[4], wv[4];
    *(float4*)&bb[0] = *(const float4*)(bv1 + tn*4);
    *(float4*)&wv[0] = *(const float4*)(wv2 + tn*4);
    float bv2v = bv2[0];
    #pragma unroll
    for (int i = 0; i < 8; ++i){
        float v = 0.f;
        #pragma unroll
        for (int j = 0; j < 4; ++j) v = fmaf(fmaxf(acc[i][j] + bb[j], 0.f), wv[j], v);
        v += __shfl_xor(v, 1); v += __shfl_xor(v, 2);
        v += __shfl_xor(v, 4); v += __shfl_xor(v, 8);
        int node = m0 + tm*8 + i;
        if (tn == 0 && node < n)
            out[1 + node] = 1.0f / (1.0f + __expf(-(v + bv2v)));
    }
}

// ----------------- path head (1 block) -----------------
__global__ __launch_bounds__(128) void path_kernel(
        const float* __restrict__ h, const float* __restrict__ g,
        const float* __restrict__ wp1, const float* __restrict__ bp1,
        const float* __restrict__ wp2, const float* __restrict__ bp2,
        const float* __restrict__ wp3, const float* __restrict__ bp3,
        float* __restrict__ out, int n)
{
    __shared__ float pc[256];
    __shared__ float p1[HC];
    __shared__ float p2[64];
    int t = threadIdx.x;              // 128
    pc[t]       = h[t];               // h[0,:]
    pc[128 + t] = g[t] * (1.0f / (float)n);
    __syncthreads();
    float a = bp1[t];
    for (int k = 0; k < 256; ++k) a = fmaf(pc[k], wp1[k * HC + t], a);
    p1[t] = fmaxf(a, 0.f);
    __syncthreads();
    if (t < 64){
        float a2 = bp2[t];
        for (int k = 0; k < HC; ++k) a2 = fmaf(p1[k], wp2[k * 64 + t], a2);
        p2[t] = fmaxf(a2, 0.f);
    }
    __syncthreads();
    if (t == 0){
        float a3 = bp3[0];
        for (int k = 0; k < 64; ++k) a3 = fmaf(p2[k], wp3[k], a3);
        out[0] = 1.0f / (1.0f + __expf(-a3));
        out[1 + n] = 0.f;             // esc = 0
    }
}

extern "C" void kernel_launch(void* const* d_in, const int* in_sizes, int n_in,
                              void* d_out, int out_size, void* d_ws, size_t ws_size,
                              hipStream_t stream)
{
    const float* x    = (const float*)d_in[0];
    const int*   ei   = (const int*)d_in[1];
    // d_in[2] edge_attr: computed-but-ignored by reference -> never touched
    const float* w_n1 = (const float*)d_in[3];
    const float* b_n1 = (const float*)d_in[4];
    const float* w_n2 = (const float*)d_in[5];
    const float* b_n2 = (const float*)d_in[6];
    // d_in[7..8] edge encoder: unused
    const float* conv_w = (const float*)d_in[9];
    const float* att_s  = (const float*)d_in[10];
    const float* att_d  = (const float*)d_in[11];
    const float* conv_b = (const float*)d_in[12];
    const float* wp1 = (const float*)d_in[13];
    const float* bp1 = (const float*)d_in[14];
    const float* wp2 = (const float*)d_in[15];
    const float* bp2 = (const float*)d_in[16];
    const float* wp3 = (const float*)d_in[17];
    const float* bp3 = (const float*)d_in[18];
    const float* wv1 = (const float*)d_in[19];
    const float* bv1 = (const float*)d_in[20];
    const float* wv2 = (const float*)d_in[21];
    const float* bv2 = (const float*)d_in[22];

    const int N = in_sizes[0] / 32;
    const int E = in_sizes[1] / 2;
    float* out = (float*)d_out;

    char* ws = (char*)d_ws;
    size_t off = 0;
    auto take = [&](size_t bytes) -> char* {
        char* p = ws + off;
        off += (bytes + 255) & ~(size_t)255;
        return p;
    };
    float* hA    = (float*)take((size_t)N * HC * 4);
    float* hB    = (float*)take((size_t)N * HC * 4);
    float* asrc  = (float*)take((size_t)N * 2 * 4);
    float* adst  = (float*)take((size_t)N * 2 * 4);
    int*   rowptr= (int*)take((size_t)(N + 1) * 4);
    int*   cursor= (int*)take((size_t)N * 4);
    int*   colsrc= (int*)take((size_t)E * 4);
    float* g     = (float*)take(HC * 4);

    // --- CSR build (dst-sorted; reused across the 3 layers) ---
    hipMemsetAsync(cursor, 0, (size_t)N * 4, stream);
    count_kernel<<<(E + 255) / 256, 256, 0, stream>>>(ei, cursor, E);
    scan_kernel<<<1, 1024, 0, stream>>>(cursor, rowptr, N);
    hipMemsetAsync(cursor, 0, (size_t)N * 4, stream);
    scatter_kernel<<<(E + 255) / 256, 256, 0, stream>>>(ei, rowptr, cursor, colsrc, E);

    int nblk = (N + 127) / 128;
    // node encoder: hid (hB) = relu(x@w1+b1); hA = hid@w2 + b2
    enc1_kernel<<<nblk, 256, 0, stream>>>(x, w_n1, b_n1, hB, N);
    gemm_main_kernel<false><<<nblk, 256, 0, stream>>>(
        hB, w_n2, b_n2, nullptr, nullptr, hA, nullptr, nullptr, N);

    for (int l = 0; l < 3; ++l){
        gemm_main_kernel<true><<<nblk, 256, 0, stream>>>(
            hA, conv_w + (size_t)l * HC * HC, nullptr,
            att_s + (size_t)l * HC, att_d + (size_t)l * HC,
            hB, asrc, adst, N);
        aggregate_kernel<<<N, 64, 0, stream>>>(
            hB, asrc, adst, rowptr, colsrc, conv_b + (size_t)l * HC, hA, N);
    }

    hipMemsetAsync(g, 0, HC * 4, stream);
    mean_kernel<<<256, 128, 0, stream>>>(hA, g, N);
    vuln_fused_kernel<<<nblk, 256, 0, stream>>>(hA, wv1, bv1, wv2, bv2, out, N);
    path_kernel<<<1, 128, 0, stream>>>(hA, g, wp1, bp1, wp2, bp2, wp3, bp3, out, N);
}

// Round 3
// 439.307 us; speedup vs baseline: 2.6590x; 1.3405x over previous
//
#include <hip/hip_runtime.h>
#include <math.h>

#define HC 128
#define NSLOPE 0.2f

__device__ __forceinline__ float lrelu(float v){ return v > 0.f ? v : NSLOPE * v; }

// bf16 round-to-nearest-even pack / unpack
__device__ __forceinline__ unsigned short f2bf(float f){
    unsigned int b = __float_as_uint(f);
    b += 0x7FFFu + ((b >> 16) & 1u);
    return (unsigned short)(b >> 16);
}
__device__ __forceinline__ float bf_lo(unsigned int v){ return __uint_as_float(v << 16); }
__device__ __forceinline__ float bf_hi(unsigned int v){ return __uint_as_float(v & 0xFFFF0000u); }

// ----------------- CSR build (dst-sorted) -----------------
__global__ void count_kernel(const int* __restrict__ ei, int* __restrict__ cnt, int E){
    int e = blockIdx.x * blockDim.x + threadIdx.x;
    if (e < E) atomicAdd(&cnt[ei[E + e]], 1);
}

// S1: per-block (1024 nodes) partial sums
__global__ __launch_bounds__(256) void scan_part_kernel(
        const int* __restrict__ deg, int* __restrict__ bsum, int n)
{
    int t = threadIdx.x, lane = t & 63, wid = t >> 6;
    int base = blockIdx.x * 1024 + t * 4;
    int s = 0;
    #pragma unroll
    for (int j = 0; j < 4; ++j){ int i = base + j; if (i < n) s += deg[i]; }
    #pragma unroll
    for (int o = 1; o < 64; o <<= 1) s += __shfl_xor(s, o);
    __shared__ int red[4];
    if (lane == 0) red[wid] = s;
    __syncthreads();
    if (t == 0) bsum[blockIdx.x] = red[0] + red[1] + red[2] + red[3];
}

// S2: 1 wave scans the (<=64) block sums; writes exclusive offsets + rowptr[n]=total
__global__ __launch_bounds__(64) void scan_top_kernel(
        const int* __restrict__ bsum, int* __restrict__ boff, int* __restrict__ rowptr,
        int nb, int n)
{
    int t = threadIdx.x;
    int v = (t < nb) ? bsum[t] : 0;
    int incl = v;
    #pragma unroll
    for (int o = 1; o < 64; o <<= 1){ int u = __shfl_up(incl, o); if (t >= o) incl += u; }
    if (t < nb) boff[t] = incl - v;
    if (t == 63) rowptr[n] = incl;
}

// S3: per-block exclusive scan with global offset -> rowptr[0..n-1]
__global__ __launch_bounds__(256) void scan_fin_kernel(
        const int* __restrict__ deg, const int* __restrict__ boff,
        int* __restrict__ rowptr, int n)
{
    int t = threadIdx.x, lane = t & 63, wid = t >> 6;
    int base = blockIdx.x * 1024 + t * 4;
    int d[4]; int s = 0;
    #pragma unroll
    for (int j = 0; j < 4; ++j){ int i = base + j; d[j] = (i < n) ? deg[i] : 0; s += d[j]; }
    int incl = s;
    #pragma unroll
    for (int o = 1; o < 64; o <<= 1){ int u = __shfl_up(incl, o); if (lane >= o) incl += u; }
    __shared__ int wsum[4];
    if (lane == 63) wsum[wid] = incl;
    __syncthreads();
    int off = boff[blockIdx.x] + (incl - s);
    for (int w = 0; w < wid; ++w) off += wsum[w];
    #pragma unroll
    for (int j = 0; j < 4; ++j){
        int i = base + j;
        if (i < n) rowptr[i] = off;
        off += d[j];
    }
}

__global__ void scatter_kernel(const int* __restrict__ ei, const int* __restrict__ rowptr,
                               int* __restrict__ cursor, int* __restrict__ colsrc, int E){
    int e = blockIdx.x * blockDim.x + threadIdx.x;
    if (e < E){
        int d = ei[E + e];
        int pos = rowptr[d] + atomicAdd(&cursor[d], 1);
        colsrc[pos] = ei[e];
    }
}

// ----------------- node encoder stage 1: hid = relu(x@w1+b1), K=32 -----------------
__global__ __launch_bounds__(256) void enc1_kernel(
        const float* __restrict__ x, const float* __restrict__ w1, const float* __restrict__ b1,
        float* __restrict__ hid, int n)
{
    __shared__ float As[32][132];
    __shared__ float Bs[32][128];
    int t = threadIdx.x;
    int m0 = blockIdx.x * 128;
    int tm = t >> 4, tn = t & 15;

    #pragma unroll
    for (int i = 0; i < 4; ++i){
        int f = i * 256 + t;
        int row = f >> 3, kq = f & 7;
        int gr = m0 + row; if (gr > n - 1) gr = n - 1;
        float4 v = *(const float4*)(x + (size_t)gr * 32 + kq * 4);
        As[kq*4+0][row] = v.x; As[kq*4+1][row] = v.y; As[kq*4+2][row] = v.z; As[kq*4+3][row] = v.w;
    }
    #pragma unroll
    for (int i = 0; i < 4; ++i){
        int f = i * 256 + t;
        int kk = f >> 5, nq = f & 31;
        *(float4*)&Bs[kk][nq*4] = *(const float4*)(w1 + (size_t)kk * 128 + nq * 4);
    }
    __syncthreads();

    float acc[8][8];
    #pragma unroll
    for (int i = 0; i < 8; ++i)
        #pragma unroll
        for (int j = 0; j < 8; ++j) acc[i][j] = 0.f;

    #pragma unroll 4
    for (int k = 0; k < 32; ++k){
        float a[8], b[8];
        *(float4*)&a[0] = *(float4*)&As[k][tm*8];
        *(float4*)&a[4] = *(float4*)&As[k][tm*8+4];
        *(float4*)&b[0] = *(float4*)&Bs[k][tn*8];
        *(float4*)&b[4] = *(float4*)&Bs[k][tn*8+4];
        #pragma unroll
        for (int i = 0; i < 8; ++i)
            #pragma unroll
            for (int j = 0; j < 8; ++j) acc[i][j] = fmaf(a[i], b[j], acc[i][j]);
    }

    float bb[8];
    *(float4*)&bb[0] = *(const float4*)(b1 + tn*8);
    *(float4*)&bb[4] = *(const float4*)(b1 + tn*8 + 4);
    #pragma unroll
    for (int i = 0; i < 8; ++i){
        int node = m0 + tm*8 + i;
        if (node < n){
            float o[8];
            #pragma unroll
            for (int j = 0; j < 8; ++j) o[j] = fmaxf(acc[i][j] + bb[j], 0.f);
            *(float4*)(hid + (size_t)node*HC + tn*8)     = *(float4*)&o[0];
            *(float4*)(hid + (size_t)node*HC + tn*8 + 4) = *(float4*)&o[4];
        }
    }
}

// ----------------- main GEMM: C = A@W (+bias); ATT: bf16 C + fused att dots -----------------
template<bool ATT>
__global__ __launch_bounds__(256) void gemm_main_kernel(
        const float* __restrict__ A, const float* __restrict__ W, const float* __restrict__ bias,
        const float* __restrict__ att_s, const float* __restrict__ att_d,
        float* __restrict__ C, unsigned short* __restrict__ Cb,
        float* __restrict__ asrc, float* __restrict__ adst, int n)
{
    __shared__ float As[32][132];
    __shared__ float Bs[32][128];
    int t = threadIdx.x;
    int m0 = blockIdx.x * 128;
    int tm = t >> 4, tn = t & 15;

    float acc[8][8];
    #pragma unroll
    for (int i = 0; i < 8; ++i)
        #pragma unroll
        for (int j = 0; j < 8; ++j) acc[i][j] = 0.f;

    for (int kc = 0; kc < 4; ++kc){
        int k0 = kc * 32;
        #pragma unroll
        for (int i = 0; i < 4; ++i){
            int f = i * 256 + t;
            int row = f >> 3, kq = f & 7;
            int gr = m0 + row; if (gr > n - 1) gr = n - 1;
            float4 v = *(const float4*)(A + (size_t)gr * HC + k0 + kq * 4);
            As[kq*4+0][row] = v.x; As[kq*4+1][row] = v.y; As[kq*4+2][row] = v.z; As[kq*4+3][row] = v.w;
        }
        #pragma unroll
        for (int i = 0; i < 4; ++i){
            int f = i * 256 + t;
            int kk = f >> 5, nq = f & 31;
            *(float4*)&Bs[kk][nq*4] = *(const float4*)(W + (size_t)(k0 + kk) * 128 + nq * 4);
        }
        __syncthreads();
        #pragma unroll 4
        for (int k = 0; k < 32; ++k){
            float a[8], b[8];
            *(float4*)&a[0] = *(float4*)&As[k][tm*8];
            *(float4*)&a[4] = *(float4*)&As[k][tm*8+4];
            *(float4*)&b[0] = *(float4*)&Bs[k][tn*8];
            *(float4*)&b[4] = *(float4*)&Bs[k][tn*8+4];
            #pragma unroll
            for (int i = 0; i < 8; ++i)
                #pragma unroll
                for (int j = 0; j < 8; ++j) acc[i][j] = fmaf(a[i], b[j], acc[i][j]);
        }
        __syncthreads();
    }

    if (!ATT){
        float bb[8];
        *(float4*)&bb[0] = *(const float4*)(bias + tn*8);
        *(float4*)&bb[4] = *(const float4*)(bias + tn*8 + 4);
        #pragma unroll
        for (int i = 0; i < 8; ++i){
            int node = m0 + tm*8 + i;
            if (node < n){
                float o[8];
                #pragma unroll
                for (int j = 0; j < 8; ++j) o[j] = acc[i][j] + bb[j];
                *(float4*)(C + (size_t)node*HC + tn*8)     = *(float4*)&o[0];
                *(float4*)(C + (size_t)node*HC + tn*8 + 4) = *(float4*)&o[4];
            }
        }
    } else {
        #pragma unroll
        for (int i = 0; i < 8; ++i){
            int node = m0 + tm*8 + i;
            if (node < n){
                uint4 pk;
                pk.x = (unsigned int)f2bf(acc[i][0]) | ((unsigned int)f2bf(acc[i][1]) << 16);
                pk.y = (unsigned int)f2bf(acc[i][2]) | ((unsigned int)f2bf(acc[i][3]) << 16);
                pk.z = (unsigned int)f2bf(acc[i][4]) | ((unsigned int)f2bf(acc[i][5]) << 16);
                pk.w = (unsigned int)f2bf(acc[i][6]) | ((unsigned int)f2bf(acc[i][7]) << 16);
                *(uint4*)(Cb + (size_t)node*HC + tn*8) = pk;
            }
        }
        float ats[8], atd[8];
        *(float4*)&ats[0] = *(const float4*)(att_s + tn*8);
        *(float4*)&ats[4] = *(const float4*)(att_s + tn*8 + 4);
        *(float4*)&atd[0] = *(const float4*)(att_d + tn*8);
        *(float4*)&atd[4] = *(const float4*)(att_d + tn*8 + 4);
        #pragma unroll
        for (int i = 0; i < 8; ++i){
            float sa = 0.f, sd = 0.f;
            #pragma unroll
            for (int j = 0; j < 8; ++j){
                sa = fmaf(acc[i][j], ats[j], sa);
                sd = fmaf(acc[i][j], atd[j], sd);
            }
            sa += __shfl_xor(sa, 1); sa += __shfl_xor(sa, 2); sa += __shfl_xor(sa, 4);
            sd += __shfl_xor(sd, 1); sd += __shfl_xor(sd, 2); sd += __shfl_xor(sd, 4);
            int node = m0 + tm*8 + i;
            if ((tn == 0 || tn == 8) && node < n){
                int head = tn >> 3;
                asrc[(size_t)node*2 + head] = sa;
                adst[(size_t)node*2 + head] = sd;
            }
        }
    }
}

// ----------------- aggregation: out = relu( (Σ ex·h'[src]) / (Σ ex) + b ), h' in bf16 -----------------
__global__ __launch_bounds__(64) void aggregate_kernel(
        const unsigned short* __restrict__ h1b, const float* __restrict__ asrc, const float* __restrict__ adst,
        const int* __restrict__ rowptr, const int* __restrict__ colsrc,
        const float* __restrict__ bias, float* __restrict__ hout, int n)
{
    int i = blockIdx.x;
    if (i >= n) return;
    int t = threadIdx.x;              // 64 threads, 2 channels each (one uint of 2 bf16)
    int head = t >> 5;
    float ad = adst[(size_t)i*2 + head];
    float ex = __expf(lrelu(asrc[(size_t)i*2 + head] + ad));   // self loop
    unsigned int hv = ((const unsigned int*)(h1b + (size_t)i * HC))[t];
    float acc0 = ex * bf_lo(hv), acc1 = ex * bf_hi(hv), D = ex;
    int e  = rowptr[i];
    int e1 = rowptr[i + 1];
    for (; e + 2 <= e1; e += 2){       // 2-way unroll: overlap dependent gather chains
        int s0 = colsrc[e], s1 = colsrc[e + 1];
        float a0 = asrc[(size_t)s0*2 + head];
        float a1 = asrc[(size_t)s1*2 + head];
        unsigned int v0 = ((const unsigned int*)(h1b + (size_t)s0 * HC))[t];
        unsigned int v1 = ((const unsigned int*)(h1b + (size_t)s1 * HC))[t];
        float ex0 = __expf(lrelu(a0 + ad));
        float ex1 = __expf(lrelu(a1 + ad));
        acc0 = fmaf(ex0, bf_lo(v0), acc0);
        acc1 = fmaf(ex0, bf_hi(v0), acc1);
        acc0 = fmaf(ex1, bf_lo(v1), acc0);
        acc1 = fmaf(ex1, bf_hi(v1), acc1);
        D += ex0 + ex1;
    }
    if (e < e1){
        int s = colsrc[e];
        float exx = __expf(lrelu(asrc[(size_t)s*2 + head] + ad));
        unsigned int v = ((const unsigned int*)(h1b + (size_t)s * HC))[t];
        acc0 = fmaf(exx, bf_lo(v), acc0);
        acc1 = fmaf(exx, bf_hi(v), acc1);
        D += exx;
    }
    float rD = 1.0f / D;
    float o0 = fmaxf(acc0 * rD + bias[2*t],     0.f);
    float o1 = fmaxf(acc1 * rD + bias[2*t + 1], 0.f);
    ((float2*)(hout + (size_t)i * HC))[t] = make_float2(o0, o1);
}

// ----------------- graph mean -----------------
__global__ void mean_kernel(const float* __restrict__ h, float* __restrict__ g, int n){
    int c = threadIdx.x;              // 128
    float acc = 0.f;
    for (int i = blockIdx.x; i < n; i += gridDim.x)
        acc += h[(size_t)i * HC + c];
    atomicAdd(&g[c], acc);
}

// ----------------- vuln head: sigmoid(relu(h@wv1+bv1)@wv2+bv2), tiled -----------------
__global__ __launch_bounds__(256) void vuln_fused_kernel(
        const float* __restrict__ h, const float* __restrict__ wv1, const float* __restrict__ bv1,
        const float* __restrict__ wv2, const float* __restrict__ bv2,
        float* __restrict__ out, int n)
{
    __shared__ float As[32][132];
    __shared__ float Bs[32][64];
    int t = threadIdx.x;
    int m0 = blockIdx.x * 128;
    int tm = t >> 4, tn = t & 15;

    float acc[8][4];
    #pragma unroll
    for (int i = 0; i < 8; ++i)
        #pragma unroll
        for (int j = 0; j < 4; ++j) acc[i][j] = 0.f;

    for (int kc = 0; kc < 4; ++kc){
        int k0 = kc * 32;
        #pragma unroll
        for (int i = 0; i < 4; ++i){
            int f = i * 256 + t;
            int row = f >> 3, kq = f & 7;
            int gr = m0 + row; if (gr > n - 1) gr = n - 1;
            float4 v = *(const float4*)(h + (size_t)gr * HC + k0 + kq * 4);
            As[kq*4+0][row] = v.x; As[kq*4+1][row] = v.y; As[kq*4+2][row] = v.z; As[kq*4+3][row] = v.w;
        }
        #pragma unroll
        for (int i = 0; i < 2; ++i){
            int f = i * 256 + t;
            int kk = f >> 4, nq = f & 15;
            *(float4*)&Bs[kk][nq*4] = *(const float4*)(wv1 + (size_t)(k0 + kk) * 64 + nq * 4);
        }
        __syncthreads();
        #pragma unroll 4
        for (int k = 0; k < 32; ++k){
            float a[8], b[4];
            *(float4*)&a[0] = *(float4*)&As[k][tm*8];
            *(float4*)&a[4] = *(float4*)&As[k][tm*8+4];
            *(float4*)&b[0] = *(float4*)&Bs[k][tn*4];
            #pragma unroll
            for (int i = 0; i < 8; ++i)
                #pragma unroll
                for (int j = 0; j < 4; ++j) acc[i][j] = fmaf(a[i], b[j], acc[i][j]);
        }
        __syncthreads();
    }

    float bb[4], wv[4];
    *(float4*)&bb[0] = *(const float4*)(bv1 + tn*4);
    *(float4*)&wv[0] = *(const float4*)(wv2 + tn*4);
    float bv2v = bv2[0];
    #pragma unroll
    for (int i = 0; i < 8; ++i){
        float v = 0.f;
        #pragma unroll
        for (int j = 0; j < 4; ++j) v = fmaf(fmaxf(acc[i][j] + bb[j], 0.f), wv[j], v);
        v += __shfl_xor(v, 1); v += __shfl_xor(v, 2);
        v += __shfl_xor(v, 4); v += __shfl_xor(v, 8);
        int node = m0 + tm*8 + i;
        if (tn == 0 && node < n)
            out[1 + node] = 1.0f / (1.0f + __expf(-(v + bv2v)));
    }
}

// ----------------- path head (1 block) -----------------
__global__ __launch_bounds__(128) void path_kernel(
        const float* __restrict__ h, const float* __restrict__ g,
        const float* __restrict__ wp1, const float* __restrict__ bp1,
        const float* __restrict__ wp2, const float* __restrict__ bp2,
        const float* __restrict__ wp3, const float* __restrict__ bp3,
        float* __restrict__ out, int n)
{
    __shared__ float pc[256];
    __shared__ float p1[HC];
    __shared__ float p2[64];
    int t = threadIdx.x;              // 128
    pc[t]       = h[t];               // h[0,:]
    pc[128 + t] = g[t] * (1.0f / (float)n);
    __syncthreads();
    float a = bp1[t];
    for (int k = 0; k < 256; ++k) a = fmaf(pc[k], wp1[k * HC + t], a);
    p1[t] = fmaxf(a, 0.f);
    __syncthreads();
    if (t < 64){
        float a2 = bp2[t];
        for (int k = 0; k < HC; ++k) a2 = fmaf(p1[k], wp2[k * 64 + t], a2);
        p2[t] = fmaxf(a2, 0.f);
    }
    __syncthreads();
    if (t == 0){
        float a3 = bp3[0];
        for (int k = 0; k < 64; ++k) a3 = fmaf(p2[k], wp3[k], a3);
        out[0] = 1.0f / (1.0f + __expf(-a3));
        out[1 + n] = 0.f;             // esc = 0
    }
}

extern "C" void kernel_launch(void* const* d_in, const int* in_sizes, int n_in,
                              void* d_out, int out_size, void* d_ws, size_t ws_size,
                              hipStream_t stream)
{
    const float* x    = (const float*)d_in[0];
    const int*   ei   = (const int*)d_in[1];
    const float* w_n1 = (const float*)d_in[3];
    const float* b_n1 = (const float*)d_in[4];
    const float* w_n2 = (const float*)d_in[5];
    const float* b_n2 = (const float*)d_in[6];
    const float* conv_w = (const float*)d_in[9];
    const float* att_s  = (const float*)d_in[10];
    const float* att_d  = (const float*)d_in[11];
    const float* conv_b = (const float*)d_in[12];
    const float* wp1 = (const float*)d_in[13];
    const float* bp1 = (const float*)d_in[14];
    const float* wp2 = (const float*)d_in[15];
    const float* bp2 = (const float*)d_in[16];
    const float* wp3 = (const float*)d_in[17];
    const float* bp3 = (const float*)d_in[18];
    const float* wv1 = (const float*)d_in[19];
    const float* bv1 = (const float*)d_in[20];
    const float* wv2 = (const float*)d_in[21];
    const float* bv2 = (const float*)d_in[22];

    const int N = in_sizes[0] / 32;
    const int E = in_sizes[1] / 2;
    float* out = (float*)d_out;

    char* ws = (char*)d_ws;
    size_t off = 0;
    auto take = [&](size_t bytes) -> char* {
        char* p = ws + off;
        off += (bytes + 255) & ~(size_t)255;
        return p;
    };
    float* hA    = (float*)take((size_t)N * HC * 4);
    float* hB    = (float*)take((size_t)N * HC * 4);   // f32 hid OR bf16 h' (reused)
    float* asrc  = (float*)take((size_t)N * 2 * 4);
    float* adst  = (float*)take((size_t)N * 2 * 4);
    int*   rowptr= (int*)take((size_t)(N + 1) * 4);
    int*   cursor= (int*)take((size_t)N * 4);
    int*   colsrc= (int*)take((size_t)E * 4);
    float* g     = (float*)take(HC * 4);
    int nb = (N + 1023) / 1024;
    int*   bsum  = (int*)take((size_t)((nb + 63) & ~63) * 4);
    int*   boff  = (int*)take((size_t)((nb + 63) & ~63) * 4);
    unsigned short* hBb = (unsigned short*)hB;

    // --- CSR build (dst-sorted; reused across the 3 layers) ---
    hipMemsetAsync(cursor, 0, (size_t)N * 4, stream);
    count_kernel<<<(E + 255) / 256, 256, 0, stream>>>(ei, cursor, E);
    scan_part_kernel<<<nb, 256, 0, stream>>>(cursor, bsum, N);
    scan_top_kernel<<<1, 64, 0, stream>>>(bsum, boff, rowptr, nb, N);
    scan_fin_kernel<<<nb, 256, 0, stream>>>(cursor, boff, rowptr, N);
    hipMemsetAsync(cursor, 0, (size_t)N * 4, stream);
    scatter_kernel<<<(E + 255) / 256, 256, 0, stream>>>(ei, rowptr, cursor, colsrc, E);

    int nblk = (N + 127) / 128;
    // node encoder: hid (hB f32) = relu(x@w1+b1); hA = hid@w2 + b2
    enc1_kernel<<<nblk, 256, 0, stream>>>(x, w_n1, b_n1, hB, N);
    gemm_main_kernel<false><<<nblk, 256, 0, stream>>>(
        hB, w_n2, b_n2, nullptr, nullptr, hA, nullptr, nullptr, nullptr, N);

    for (int l = 0; l < 3; ++l){
        gemm_main_kernel<true><<<nblk, 256, 0, stream>>>(
            hA, conv_w + (size_t)l * HC * HC, nullptr,
            att_s + (size_t)l * HC, att_d + (size_t)l * HC,
            nullptr, hBb, asrc, adst, N);
        aggregate_kernel<<<N, 64, 0, stream>>>(
            hBb, asrc, adst, rowptr, colsrc, conv_b + (size_t)l * HC, hA, N);
    }

    hipMemsetAsync(g, 0, HC * 4, stream);
    mean_kernel<<<256, 128, 0, stream>>>(hA, g, N);
    vuln_fused_kernel<<<nblk, 256, 0, stream>>>(hA, wv1, bv1, wv2, bv2, out, N);
    path_kernel<<<1, 128, 0, stream>>>(hA, g, wp1, bp1, wp2, bp2, wp3, bp3, out, N);
}